// Round 18
// baseline (376.775 us; speedup 1.0000x reference)
//
#include <hip/hip_runtime.h>
#include <hip/hip_bf16.h>

#define H     256
#define BM    128
#define NTHR  512
#define LDK2  264    // 256 + 8 pad (ushorts): row stride 528 B

typedef __attribute__((ext_vector_type(4)))  float f32x4;
typedef __attribute__((ext_vector_type(16))) float f32x16;
typedef __attribute__((ext_vector_type(8)))  short bf16x8;

__device__ __forceinline__ ushort f2bf(float f) {
    union { __hip_bfloat16 b; ushort u; } v;
    v.b = __float2bfloat16(f);
    return v.u;
}
__device__ __forceinline__ float bf2f(ushort h) {
    union { unsigned u; float f; } v; v.u = ((unsigned)h) << 16;
    return v.f;
}
__device__ __forceinline__ float sigmoid_f(float x) {
    return __builtin_amdgcn_rcpf(1.0f + __expf(-x));
}
__device__ __forceinline__ float tanh_f(float x) {
    float ax = fabsf(x);
    float e  = __expf(-2.0f * ax);
    float t  = (1.0f - e) * __builtin_amdgcn_rcpf(1.0f + e);
    return copysignf(t, x);
}

// --- weight prep: f32 [k][n] -> bf16 panels [n][k] in d_ws ---
// rows 0..255 = r cols (k<256: W_r, k>=256: U_r); 256..511 = z; 512..767 = h
__global__ void prep_w(const float* __restrict__ Wr, const float* __restrict__ Wz,
                       const float* __restrict__ Wh, const float* __restrict__ Ur,
                       const float* __restrict__ Uz, const float* __restrict__ Uh,
                       ushort* __restrict__ P)
{
    const int k  = blockIdx.x;          // 0..511
    const int kk = k & 255;
    const bool hi = k >= 256;
    for (int n = threadIdx.x; n < 768; n += 256) {
        float v;
        if (n < 256)      v = (hi ? Ur : Wr)[kk * 256 + n];
        else if (n < 512) v = (hi ? Uz : Wz)[kk * 256 + (n - 256)];
        else              v = (hi ? Uh : Wh)[kk * 256 + (n - 512)];
        P[(size_t)n * 512 + k] = f2bf(v);
    }
}

#define MFMA32(a, b, c) __builtin_amdgcn_mfma_f32_32x32x16_bf16((a), (b), (c), 0, 0, 0)

// B fragment loads: b-step <16 -> W half (ko=b*16), >=16 -> U half (256+)
#define LBR(B, D)  do { const int ko_ = ((B) < 16) ? (B) * 16 : 256 + ((B) - 16) * 16; \
                        D = *(const bf16x8*)(pBr + ko_); } while (0)
#define LBZ(B, D)  do { const int ko_ = ((B) < 16) ? (B) * 16 : 256 + ((B) - 16) * 16; \
                        D = *(const bf16x8*)(pBz + ko_); } while (0)
#define LBHW(B, D) do { D = *(const bf16x8*)(pBh + (B) * 16); } while (0)
#define LBHU(B, D) do { D = *(const bf16x8*)(pBh + 256 + (B) * 16); } while (0)

// region A step on sb0: 4 ds_reads -> 12 MFMAs (r, z, and mgn@W_h share af)
#define STEPA(S, RR, ZZ, HH) do {                                             \
    const int kk_ = (S) * 16;                                                 \
    bf16x8 a0_ = *(const bf16x8*)&sb0[(l31) * LDK2 + kk_ + hi8];              \
    bf16x8 a1_ = *(const bf16x8*)&sb0[(32 + l31) * LDK2 + kk_ + hi8];         \
    aR[0] = MFMA32(a0_, RR, aR[0]);                                           \
    aZ[0] = MFMA32(a0_, ZZ, aZ[0]);                                           \
    aH[0] = MFMA32(a0_, HH, aH[0]);                                           \
    aR[1] = MFMA32(a1_, RR, aR[1]);                                           \
    aZ[1] = MFMA32(a1_, ZZ, aZ[1]);                                           \
    aH[1] = MFMA32(a1_, HH, aH[1]);                                           \
    bf16x8 a2_ = *(const bf16x8*)&sb0[(64 + l31) * LDK2 + kk_ + hi8];         \
    bf16x8 a3_ = *(const bf16x8*)&sb0[(96 + l31) * LDK2 + kk_ + hi8];         \
    aR[2] = MFMA32(a2_, RR, aR[2]);                                           \
    aZ[2] = MFMA32(a2_, ZZ, aZ[2]);                                           \
    aH[2] = MFMA32(a2_, HH, aH[2]);                                           \
    aR[3] = MFMA32(a3_, RR, aR[3]);                                           \
    aZ[3] = MFMA32(a3_, ZZ, aZ[3]);                                           \
    aH[3] = MFMA32(a3_, HH, aH[3]);                                           \
} while (0)

// region B step on sb1 (joint @ U_r|U_z): 4 ds_reads -> 8 MFMAs
#define STEPB(S, RR, ZZ) do {                                                 \
    const int kk_ = (S) * 16;                                                 \
    bf16x8 a0_ = *(const bf16x8*)&sb1[(l31) * LDK2 + kk_ + hi8];              \
    bf16x8 a1_ = *(const bf16x8*)&sb1[(32 + l31) * LDK2 + kk_ + hi8];         \
    aR[0] = MFMA32(a0_, RR, aR[0]);                                           \
    aZ[0] = MFMA32(a0_, ZZ, aZ[0]);                                           \
    aR[1] = MFMA32(a1_, RR, aR[1]);                                           \
    aZ[1] = MFMA32(a1_, ZZ, aZ[1]);                                           \
    bf16x8 a2_ = *(const bf16x8*)&sb1[(64 + l31) * LDK2 + kk_ + hi8];         \
    bf16x8 a3_ = *(const bf16x8*)&sb1[(96 + l31) * LDK2 + kk_ + hi8];         \
    aR[2] = MFMA32(a2_, RR, aR[2]);                                           \
    aZ[2] = MFMA32(a2_, ZZ, aZ[2]);                                           \
    aR[3] = MFMA32(a3_, RR, aR[3]);                                           \
    aZ[3] = MFMA32(a3_, ZZ, aZ[3]);                                           \
} while (0)

// region C step on sb1 (a @ U_h): 4 ds_reads -> 4 MFMAs
#define STEPC(S, HH) do {                                                     \
    const int kk_ = (S) * 16;                                                 \
    bf16x8 a0_ = *(const bf16x8*)&sb1[(l31) * LDK2 + kk_ + hi8];              \
    bf16x8 a1_ = *(const bf16x8*)&sb1[(32 + l31) * LDK2 + kk_ + hi8];         \
    aH[0] = MFMA32(a0_, HH, aH[0]);                                           \
    aH[1] = MFMA32(a1_, HH, aH[1]);                                           \
    bf16x8 a2_ = *(const bf16x8*)&sb1[(64 + l31) * LDK2 + kk_ + hi8];         \
    bf16x8 a3_ = *(const bf16x8*)&sb1[(96 + l31) * LDK2 + kk_ + hi8];         \
    aH[2] = MFMA32(a2_, HH, aH[2]);                                           \
    aH[3] = MFMA32(a3_, HH, aH[3]);                                           \
} while (0)

// joint staging: 2-f32x4 chunks (8 regs), issue early / commit 2 steps later
#define LOADJ(C) do {                                                         \
    _Pragma("unroll") for (int i_ = 0; i_ < 2; ++i_) {                        \
        const int c_ = tid + ((C) * 2 + i_) * NTHR;                           \
        jv[i_] = *(const f32x4*)(joint + (r0 + (c_ >> 6)) * H + (c_ & 63) * 4); \
    }                                                                         \
} while (0)

#define COMMITJ(C) do {                                                       \
    _Pragma("unroll") for (int i_ = 0; i_ < 2; ++i_) {                        \
        const int c_ = tid + ((C) * 2 + i_) * NTHR;                           \
        ushort4 w_;                                                           \
        w_.x = f2bf(jv[i_][0]); w_.y = f2bf(jv[i_][1]);                       \
        w_.z = f2bf(jv[i_][2]); w_.w = f2bf(jv[i_][3]);                       \
        *(ushort4*)&sb1[(c_ >> 6) * LDK2 + (c_ & 63) * 4] = w_;               \
    }                                                                         \
} while (0)

__global__ __launch_bounds__(NTHR, 2)
void gru_main(const float* __restrict__ joint, const float* __restrict__ mgn,
              const ushort* __restrict__ P,
              const float* __restrict__ br_, const float* __restrict__ bz_,
              const float* __restrict__ bh_, float* __restrict__ out)
{
    __shared__ ushort sb0[BM * LDK2];   // mgn bf16
    __shared__ ushort sb1[BM * LDK2];   // joint bf16 -> a = joint*r

    const int tid  = threadIdx.x;
    const int wave = tid >> 6;          // 0..7
    const int lane = tid & 63;
    const int l31  = lane & 31;
    const int hi8  = (lane >> 5) * 8;   // A/B frag k-offset
    const int hi4  = (lane >> 5) * 4;   // C/D row offset
    const int colbase = wave * 32;      // 8 waves x 32 cols: B read once per block
    const int col  = colbase + l31;
    const size_t r0 = (size_t)blockIdx.x * BM;

    const ushort* __restrict__ pBr = P + (size_t)col * 512 + hi8;
    const ushort* __restrict__ pBz = pBr + (size_t)256 * 512;
    const ushort* __restrict__ pBh = pBr + (size_t)512 * 512;

    // --- stage mgn -> sb0 fully upfront (2 batches of 8 f32x4) ---
    #pragma unroll
    for (int b = 0; b < 2; ++b) {
        f32x4 mv[8];
        #pragma unroll
        for (int i = 0; i < 8; ++i) {
            const int c = tid + (b * 8 + i) * NTHR;
            mv[i] = *(const f32x4*)(mgn + (r0 + (c >> 6)) * H + (c & 63) * 4);
        }
        #pragma unroll
        for (int i = 0; i < 8; ++i) {
            const int c = tid + (b * 8 + i) * NTHR;
            ushort4 w;
            w.x = f2bf(mv[i][0]); w.y = f2bf(mv[i][1]);
            w.z = f2bf(mv[i][2]); w.w = f2bf(mv[i][3]);
            *(ushort4*)&sb0[(c >> 6) * LDK2 + (c & 63) * 4] = w;
        }
    }
    __syncthreads();

    f32x16 aR[4], aZ[4], aH[4];
    #pragma unroll
    for (int rf = 0; rf < 4; ++rf)
        #pragma unroll
        for (int e = 0; e < 16; ++e) { aR[rf][e] = 0.f; aZ[rf][e] = 0.f; aH[rf][e] = 0.f; }

    // --- region A: 16 steps on sb0 -> aR,aZ,aH (r,z + mgn@W_h fused, 12 MFMA/step);
    //     joint -> sb1 staged in 8x2 chunks; B rolls depth-2 ---
    {
        f32x4 jv[2];
        bf16x8 wR[2], wZ[2], wH[2];
        LBR(0, wR[0]); LBZ(0, wZ[0]); LBHW(0, wH[0]);
        LBR(1, wR[1]); LBZ(1, wZ[1]); LBHW(1, wH[1]);
        LOADJ(0);
        #pragma unroll
        for (int s = 0; s < 16; ++s) {
            STEPA(s, wR[s & 1], wZ[s & 1], wH[s & 1]);
            LBR(s + 2, wR[s & 1]);          // s=14,15 preload U-half b16,17 for region B
            LBZ(s + 2, wZ[s & 1]);
            if (s < 14) LBHW(s + 2, wH[s & 1]);
            if (s == 1)  { COMMITJ(0); LOADJ(1); }
            if (s == 3)  { COMMITJ(1); LOADJ(2); }
            if (s == 5)  { COMMITJ(2); LOADJ(3); }
            if (s == 7)  { COMMITJ(3); LOADJ(4); }
            if (s == 9)  { COMMITJ(4); LOADJ(5); }
            if (s == 11) { COMMITJ(5); LOADJ(6); }
            if (s == 13) { COMMITJ(6); LOADJ(7); }
            if (s == 15) { COMMITJ(7); }
        }
        __syncthreads();                    // sb1 (joint) complete
        // --- region B: 16 steps on sb1 -> aR,aZ (joint @ U_r|U_z) ---
        #pragma unroll
        for (int s = 0; s < 16; ++s) {
            STEPB(s, wR[s & 1], wZ[s & 1]);
            if (s < 14) { LBR(s + 18, wR[s & 1]); LBZ(s + 18, wZ[s & 1]); }
        }
    }
    __syncthreads();   // all waves done reading joint in sb1

    // --- hoist first 4 region-C B loads (independent of gates) ---
    bf16x8 wH4[4];
    LBHU(0, wH4[0]); LBHU(1, wH4[1]); LBHU(2, wH4[2]); LBHU(3, wH4[3]);

    // --- gates: r -> a (overwrite sb1); z,h packed to regs as bf16 ---
    uint hs[32], zs[32];
    {
        const float brv = br_[col];
        const float bzv = bz_[col];
        #pragma unroll
        for (int rf = 0; rf < 4; ++rf)
            #pragma unroll
            for (int m = 0; m < 16; m += 2) {
                ushort hb[2], zb[2];
                #pragma unroll
                for (int e = 0; e < 2; ++e) {
                    const int mm  = m + e;
                    const int row = rf * 32 + (mm & 3) + 8 * (mm >> 2) + hi4;
                    const int idx = row * LDK2 + col;
                    const float r = sigmoid_f(aR[rf][mm] + brv);
                    hb[e] = sb1[idx];
                    sb1[idx] = f2bf(bf2f(hb[e]) * r);
                    zb[e] = f2bf(sigmoid_f(aZ[rf][mm] + bzv));
                }
                hs[rf * 8 + (m >> 1)] = (uint)hb[0] | ((uint)hb[1] << 16);
                zs[rf * 8 + (m >> 1)] = (uint)zb[0] | ((uint)zb[1] << 16);
            }
    }
    __syncthreads();

    // --- region C: 16 steps on sb1 -> aH += a @ U_h, depth-4 roll ---
    #pragma unroll
    for (int s = 0; s < 16; ++s) {
        STEPC(s, wH4[s & 3]);
        if (s < 12) LBHU(s + 4, wH4[s & 3]);
    }

    // --- epilogue: out = ht + z*(h - ht); h,z from packed regs ---
    {
        const float bhv = bh_[col];
        #pragma unroll
        for (int rf = 0; rf < 4; ++rf)
            #pragma unroll
            for (int m = 0; m < 16; ++m) {
                const int row = rf * 32 + (m & 3) + 8 * (m >> 2) + hi4;
                const float ht = tanh_f(aH[rf][m] + bhv);
                const uint pk  = hs[rf * 8 + (m >> 1)];
                const uint pz  = zs[rf * 8 + (m >> 1)];
                const float h  = bf2f((ushort)(pk >> ((m & 1) * 16)));
                const float z  = bf2f((ushort)(pz >> ((m & 1) * 16)));
                out[(r0 + row) * H + col] = ht + z * (h - ht);
            }
    }
}

extern "C" void kernel_launch(void* const* d_in, const int* in_sizes, int n_in,
                              void* d_out, int out_size, void* d_ws, size_t ws_size,
                              hipStream_t stream)
{
    const float* joint = (const float*)d_in[0];
    const float* mgn   = (const float*)d_in[1];
    const float* Wr    = (const float*)d_in[2];
    const float* Wz    = (const float*)d_in[3];
    const float* Wh    = (const float*)d_in[4];
    const float* Ur    = (const float*)d_in[5];
    const float* Uz    = (const float*)d_in[6];
    const float* Uh    = (const float*)d_in[7];
    const float* br    = (const float*)d_in[8];
    const float* bz    = (const float*)d_in[9];
    const float* bh    = (const float*)d_in[10];

    ushort* P  = (ushort*)d_ws;          // 786 KB scratch
    float* out = (float*)d_out;

    prep_w<<<512, 256, 0, stream>>>(Wr, Wz, Wh, Ur, Uz, Uh, P);

    const int nrows = 65536;
    gru_main<<<nrows / BM, NTHR, 0, stream>>>(joint, mgn, P, br, bz, bh, out);
}

// Round 19
// 87.562 us; speedup vs baseline: 4.3029x; 4.3029x over previous
//
#include <hip/hip_runtime.h>

#define H     256
#define BM    128
#define NTHR  512
#define LDK2  264    // 256 + 8 pad (ushorts): row stride 528 B

typedef __attribute__((ext_vector_type(4)))  float f32x4;
typedef __attribute__((ext_vector_type(16))) float f32x16;
typedef __attribute__((ext_vector_type(8)))  short bf16x8;

__device__ __forceinline__ ushort f2bf(float f) {
    union { float f; unsigned u; } v; v.f = f;
    unsigned u = v.u;
    unsigned r = (u + 0x7fffu + ((u >> 16) & 1u)) >> 16;
    return (ushort)r;
}
__device__ __forceinline__ float bf2f(ushort h) {
    union { unsigned u; float f; } v; v.u = ((unsigned)h) << 16;
    return v.f;
}
__device__ __forceinline__ float sigmoid_f(float x) {
    return __builtin_amdgcn_rcpf(1.0f + __expf(-x));
}
__device__ __forceinline__ float tanh_f(float x) {
    float ax = fabsf(x);
    float e  = __expf(-2.0f * ax);
    float t  = (1.0f - e) * __builtin_amdgcn_rcpf(1.0f + e);
    return copysignf(t, x);
}

// --- weight prep: f32 [k][n] -> bf16 panels [n][k] in d_ws ---
// rows 0..255 = r cols (k<256: W_r, k>=256: U_r); 256..511 = z; 512..767 = h
__global__ void prep_w(const float* __restrict__ Wr, const float* __restrict__ Wz,
                       const float* __restrict__ Wh, const float* __restrict__ Ur,
                       const float* __restrict__ Uz, const float* __restrict__ Uh,
                       ushort* __restrict__ P)
{
    const int k  = blockIdx.x;          // 0..511
    const int kk = k & 255;
    const bool hi = k >= 256;
    for (int n = threadIdx.x; n < 768; n += 256) {
        float v;
        if (n < 256)      v = (hi ? Ur : Wr)[kk * 256 + n];
        else if (n < 512) v = (hi ? Uz : Wz)[kk * 256 + (n - 256)];
        else              v = (hi ? Uh : Wh)[kk * 256 + (n - 512)];
        P[(size_t)n * 512 + k] = f2bf(v);
    }
}

#define MFMA32(a, b, c) __builtin_amdgcn_mfma_f32_32x32x16_bf16((a), (b), (c), 0, 0, 0)

// B loads, phase 1 (r|z): b-step in [0,32): <16 -> W (ko=b*16), >=16 -> U (256+)
#define LBRZ(B, BR, BZ) do {                                                  \
    const int ko_ = ((B) < 16) ? (B) * 16 : 256 + ((B) - 16) * 16;            \
    BR = *(const bf16x8*)(pBr + ko_);                                         \
    BZ = *(const bf16x8*)(pBz + ko_);                                         \
} while (0)

// B loads, phase 2 (h): b-step <16 -> U_h (a-half, ko=256+), >=16 -> W_h (mgn)
#define LBH(B, BH) do {                                                       \
    const int ko_ = ((B) < 16) ? 256 + (B) * 16 : ((B) - 16) * 16;            \
    BH = *(const bf16x8*)(pBh + ko_);                                         \
} while (0)

// one 32x32x16 k16-step for r|z: 4 row-frags from SB at within-buffer step S16
// setprio(1) around the MFMA cluster (T5): favor MFMA-issuing wave on the SIMD
#define STEP1(SB, S16, BR, BZ) do {                                           \
    const int kk_ = (S16) * 16;                                               \
    bf16x8 af_[4];                                                            \
    _Pragma("unroll") for (int rf_ = 0; rf_ < 4; ++rf_)                       \
        af_[rf_] = *(const bf16x8*)&SB[(rf_ * 32 + l31) * LDK2 + kk_ + hi8];  \
    __builtin_amdgcn_s_setprio(1);                                            \
    _Pragma("unroll") for (int rf_ = 0; rf_ < 4; ++rf_) {                     \
        aR[rf_] = MFMA32(af_[rf_], BR, aR[rf_]);                              \
        aZ[rf_] = MFMA32(af_[rf_], BZ, aZ[rf_]);                              \
    }                                                                         \
    __builtin_amdgcn_s_setprio(0);                                            \
} while (0)

#define STEP2(SB, S16, BH) do {                                               \
    const int kk_ = (S16) * 16;                                               \
    bf16x8 af_[4];                                                            \
    _Pragma("unroll") for (int rf_ = 0; rf_ < 4; ++rf_)                       \
        af_[rf_] = *(const bf16x8*)&SB[(rf_ * 32 + l31) * LDK2 + kk_ + hi8];  \
    __builtin_amdgcn_s_setprio(1);                                            \
    _Pragma("unroll") for (int rf_ = 0; rf_ < 4; ++rf_)                       \
        aH[rf_] = MFMA32(af_[rf_], BH, aH[rf_]);                              \
    __builtin_amdgcn_s_setprio(0);                                            \
} while (0)

// mgn staging in 64-col slabs: 4 f32x4 per thread per slab
#define SLOADM(S) do {                                                        \
    _Pragma("unroll") for (int j_ = 0; j_ < 4; ++j_) {                        \
        const int u_ = j_ * NTHR + tid;                                       \
        mv[j_] = *(const f32x4*)(mgn + (r0 + (u_ >> 4)) * H + ((S) * 16 + (u_ & 15)) * 4); \
    }                                                                         \
} while (0)

#define SCOMMITM(S) do {                                                      \
    _Pragma("unroll") for (int j_ = 0; j_ < 4; ++j_) {                        \
        const int u_ = j_ * NTHR + tid;                                       \
        ushort4 w_;                                                           \
        w_.x = f2bf(mv[j_][0]); w_.y = f2bf(mv[j_][1]);                       \
        w_.z = f2bf(mv[j_][2]); w_.w = f2bf(mv[j_][3]);                       \
        *(ushort4*)&sb0[(u_ >> 4) * LDK2 + ((S) * 16 + (u_ & 15)) * 4] = w_;  \
    }                                                                         \
} while (0)

// joint staging: 2-f32x4 chunks, issue early / commit 2 steps later
#define LOADJ(C) do {                                                         \
    _Pragma("unroll") for (int i_ = 0; i_ < 2; ++i_) {                        \
        const int c_ = tid + ((C) * 2 + i_) * NTHR;                           \
        jv[i_] = *(const f32x4*)(joint + (r0 + (c_ >> 6)) * H + (c_ & 63) * 4); \
    }                                                                         \
} while (0)

#define COMMITJ(C) do {                                                       \
    _Pragma("unroll") for (int i_ = 0; i_ < 2; ++i_) {                        \
        const int c_ = tid + ((C) * 2 + i_) * NTHR;                           \
        ushort4 w_;                                                           \
        w_.x = f2bf(jv[i_][0]); w_.y = f2bf(jv[i_][1]);                       \
        w_.z = f2bf(jv[i_][2]); w_.w = f2bf(jv[i_][3]);                       \
        *(ushort4*)&sb1[(c_ >> 6) * LDK2 + (c_ & 63) * 4] = w_;               \
    }                                                                         \
} while (0)

__global__ __launch_bounds__(NTHR, 2)
void gru_main(const float* __restrict__ joint, const float* __restrict__ mgn,
              const ushort* __restrict__ P,
              const float* __restrict__ br_, const float* __restrict__ bz_,
              const float* __restrict__ bh_, float* __restrict__ out)
{
    __shared__ ushort sb0[BM * LDK2];   // mgn bf16
    __shared__ ushort sb1[BM * LDK2];   // joint bf16 -> a = joint*r

    const int tid  = threadIdx.x;
    const int wave = tid >> 6;          // 0..7
    const int lane = tid & 63;
    const int l31  = lane & 31;
    const int hi8  = (lane >> 5) * 8;   // A/B frag k-offset
    const int hi4  = (lane >> 5) * 4;   // C/D row offset
    const int colbase = wave * 32;      // 8 waves x 32 cols: B read once per block
    const int col  = colbase + l31;
    const size_t r0 = (size_t)blockIdx.x * BM;

    const ushort* __restrict__ pBr = P + (size_t)col * 512 + hi8;
    const ushort* __restrict__ pBz = pBr + (size_t)256 * 512;
    const ushort* __restrict__ pBh = pBr + (size_t)512 * 512;

    f32x4 mv[4];
    f32x4 jv[2];

    // --- slab 0 of mgn (cols 0..63) ---
    SLOADM(0); SCOMMITM(0);
    __syncthreads();

    f32x16 aR[4], aZ[4];
    #pragma unroll
    for (int rf = 0; rf < 4; ++rf)
        #pragma unroll
        for (int e = 0; e < 16; ++e) { aR[rf][e] = 0.f; aZ[rf][e] = 0.f; }

    // --- phase 1: 32 k16-steps (mgn 0-15, joint 16-31), depth-4 B roll,
    //     mgn slabs 1-3 and joint staged under MFMA ---
    {
        bf16x8 bRA, bZA, bRB, bZB, bRC, bZC, bRD, bZD;
        LBRZ(0, bRA, bZA); LBRZ(1, bRB, bZB); LBRZ(2, bRC, bZC); LBRZ(3, bRD, bZD);
        SLOADM(1); LOADJ(0);
        STEP1(sb0, 0, bRA, bZA);  LBRZ(4, bRA, bZA);
        STEP1(sb0, 1, bRB, bZB);  LBRZ(5, bRB, bZB);
        STEP1(sb0, 2, bRC, bZC);  LBRZ(6, bRC, bZC);  COMMITJ(0); LOADJ(1); SCOMMITM(1);
        STEP1(sb0, 3, bRD, bZD);  LBRZ(7, bRD, bZD);
        __syncthreads();                        // slab 1 visible
        SLOADM(2);
        STEP1(sb0, 4, bRA, bZA);  LBRZ(8, bRA, bZA);  COMMITJ(1); LOADJ(2);
        STEP1(sb0, 5, bRB, bZB);  LBRZ(9, bRB, bZB);
        STEP1(sb0, 6, bRC, bZC);  LBRZ(10, bRC, bZC); COMMITJ(2); LOADJ(3); SCOMMITM(2);
        STEP1(sb0, 7, bRD, bZD);  LBRZ(11, bRD, bZD);
        __syncthreads();                        // slab 2 visible
        SLOADM(3);
        STEP1(sb0, 8, bRA, bZA);  LBRZ(12, bRA, bZA); COMMITJ(3); LOADJ(4);
        STEP1(sb0, 9, bRB, bZB);  LBRZ(13, bRB, bZB);
        STEP1(sb0, 10, bRC, bZC); LBRZ(14, bRC, bZC); COMMITJ(4); LOADJ(5); SCOMMITM(3);
        STEP1(sb0, 11, bRD, bZD); LBRZ(15, bRD, bZD);
        __syncthreads();                        // slab 3 visible
        STEP1(sb0, 12, bRA, bZA); LBRZ(16, bRA, bZA); COMMITJ(5); LOADJ(6);
        STEP1(sb0, 13, bRB, bZB); LBRZ(17, bRB, bZB);
        STEP1(sb0, 14, bRC, bZC); LBRZ(18, bRC, bZC); COMMITJ(6); LOADJ(7);
        STEP1(sb0, 15, bRD, bZD); LBRZ(19, bRD, bZD); COMMITJ(7);
        __syncthreads();                        // sb1 (joint) complete
        STEP1(sb1, 0, bRA, bZA);  LBRZ(20, bRA, bZA);
        STEP1(sb1, 1, bRB, bZB);  LBRZ(21, bRB, bZB);
        STEP1(sb1, 2, bRC, bZC);  LBRZ(22, bRC, bZC);
        STEP1(sb1, 3, bRD, bZD);  LBRZ(23, bRD, bZD);
        STEP1(sb1, 4, bRA, bZA);  LBRZ(24, bRA, bZA);
        STEP1(sb1, 5, bRB, bZB);  LBRZ(25, bRB, bZB);
        STEP1(sb1, 6, bRC, bZC);  LBRZ(26, bRC, bZC);
        STEP1(sb1, 7, bRD, bZD);  LBRZ(27, bRD, bZD);
        STEP1(sb1, 8, bRA, bZA);  LBRZ(28, bRA, bZA);
        STEP1(sb1, 9, bRB, bZB);  LBRZ(29, bRB, bZB);
        STEP1(sb1, 10, bRC, bZC); LBRZ(30, bRC, bZC);
        STEP1(sb1, 11, bRD, bZD); LBRZ(31, bRD, bZD);
        STEP1(sb1, 12, bRA, bZA);
        STEP1(sb1, 13, bRB, bZB);
        STEP1(sb1, 14, bRC, bZC);
        STEP1(sb1, 15, bRD, bZD);
    }
    __syncthreads();   // all waves done reading joint in sb1

    // --- hoist first 4 phase-2 B loads (a-half, independent of gates) ---
    bf16x8 bHA, bHB, bHC, bHD;
    LBH(0, bHA); LBH(1, bHB); LBH(2, bHC); LBH(3, bHD);

    // --- gates: r -> a (overwrite sb1); z,h packed to regs as bf16 ---
    uint hs[32], zs[32];
    {
        const float brv = br_[col];
        const float bzv = bz_[col];
        #pragma unroll
        for (int rf = 0; rf < 4; ++rf)
            #pragma unroll
            for (int m = 0; m < 16; m += 2) {
                ushort hb[2], zb[2];
                #pragma unroll
                for (int e = 0; e < 2; ++e) {
                    const int mm  = m + e;
                    const int row = rf * 32 + (mm & 3) + 8 * (mm >> 2) + hi4;
                    const int idx = row * LDK2 + col;
                    const float r = sigmoid_f(aR[rf][mm] + brv);
                    hb[e] = sb1[idx];
                    sb1[idx] = f2bf(bf2f(hb[e]) * r);
                    zb[e] = f2bf(sigmoid_f(aZ[rf][mm] + bzv));
                }
                hs[rf * 8 + (m >> 1)] = (uint)hb[0] | ((uint)hb[1] << 16);
                zs[rf * 8 + (m >> 1)] = (uint)zb[0] | ((uint)zb[1] << 16);
            }
    }
    __syncthreads();

    // --- phase 2: 32 k16-steps (a @ U_h: sb1, then mgn @ W_h: sb0), depth-4 roll ---
    f32x16 aH[4];
    #pragma unroll
    for (int rf = 0; rf < 4; ++rf)
        #pragma unroll
        for (int e = 0; e < 16; ++e) aH[rf][e] = 0.f;

    {
        STEP2(sb1, 0, bHA);  LBH(4, bHA);
        STEP2(sb1, 1, bHB);  LBH(5, bHB);
        STEP2(sb1, 2, bHC);  LBH(6, bHC);
        STEP2(sb1, 3, bHD);  LBH(7, bHD);
        STEP2(sb1, 4, bHA);  LBH(8, bHA);
        STEP2(sb1, 5, bHB);  LBH(9, bHB);
        STEP2(sb1, 6, bHC);  LBH(10, bHC);
        STEP2(sb1, 7, bHD);  LBH(11, bHD);
        STEP2(sb1, 8, bHA);  LBH(12, bHA);
        STEP2(sb1, 9, bHB);  LBH(13, bHB);
        STEP2(sb1, 10, bHC); LBH(14, bHC);
        STEP2(sb1, 11, bHD); LBH(15, bHD);
        STEP2(sb1, 12, bHA); LBH(16, bHA);
        STEP2(sb1, 13, bHB); LBH(17, bHB);
        STEP2(sb1, 14, bHC); LBH(18, bHC);
        STEP2(sb1, 15, bHD); LBH(19, bHD);
        STEP2(sb0, 0, bHA);  LBH(20, bHA);
        STEP2(sb0, 1, bHB);  LBH(21, bHB);
        STEP2(sb0, 2, bHC);  LBH(22, bHC);
        STEP2(sb0, 3, bHD);  LBH(23, bHD);
        STEP2(sb0, 4, bHA);  LBH(24, bHA);
        STEP2(sb0, 5, bHB);  LBH(25, bHB);
        STEP2(sb0, 6, bHC);  LBH(26, bHC);
        STEP2(sb0, 7, bHD);  LBH(27, bHD);
        STEP2(sb0, 8, bHA);  LBH(28, bHA);
        STEP2(sb0, 9, bHB);  LBH(29, bHB);
        STEP2(sb0, 10, bHC); LBH(30, bHC);
        STEP2(sb0, 11, bHD); LBH(31, bHD);
        STEP2(sb0, 12, bHA);
        STEP2(sb0, 13, bHB);
        STEP2(sb0, 14, bHC);
        STEP2(sb0, 15, bHD);
    }

    // --- epilogue: out = ht + z*(h - ht); h,z from packed regs ---
    {
        const float bhv = bh_[col];
        #pragma unroll
        for (int rf = 0; rf < 4; ++rf)
            #pragma unroll
            for (int m = 0; m < 16; ++m) {
                const int row = rf * 32 + (m & 3) + 8 * (m >> 2) + hi4;
                const float ht = tanh_f(aH[rf][m] + bhv);
                const uint pk  = hs[rf * 8 + (m >> 1)];
                const uint pz  = zs[rf * 8 + (m >> 1)];
                const float h  = bf2f((ushort)(pk >> ((m & 1) * 16)));
                const float z  = bf2f((ushort)(pz >> ((m & 1) * 16)));
                out[(r0 + row) * H + col] = ht + z * (h - ht);
            }
    }
}

extern "C" void kernel_launch(void* const* d_in, const int* in_sizes, int n_in,
                              void* d_out, int out_size, void* d_ws, size_t ws_size,
                              hipStream_t stream)
{
    const float* joint = (const float*)d_in[0];
    const float* mgn   = (const float*)d_in[1];
    const float* Wr    = (const float*)d_in[2];
    const float* Wz    = (const float*)d_in[3];
    const float* Wh    = (const float*)d_in[4];
    const float* Ur    = (const float*)d_in[5];
    const float* Uz    = (const float*)d_in[6];
    const float* Uh    = (const float*)d_in[7];
    const float* br    = (const float*)d_in[8];
    const float* bz    = (const float*)d_in[9];
    const float* bh    = (const float*)d_in[10];

    ushort* P  = (ushort*)d_ws;          // 786 KB scratch
    float* out = (float*)d_out;

    prep_w<<<512, 256, 0, stream>>>(Wr, Wz, Wh, Ur, Uz, Uh, P);

    const int nrows = 65536;
    gru_main<<<nrows / BM, NTHR, 0, stream>>>(joint, mgn, P, br, bz, bh, out);
}